// Round 6
// baseline (583.281 us; speedup 1.0000x reference)
//
#include <hip/hip_runtime.h>
#include <cstdint>
#include <cstddef>

// Problem sizes (fixed by the reference)
constexpr int Bb = 64, Ss = 197, Dd = 1024, Hh = 4096;
constexpr int M  = Bb * Ss;            // 12608 tokens
constexpr int MT2 = (M + 255) / 256;   // 50 M-tiles (256-row tiles)
constexpr int Mpad = MT2 * 256;        // 12800 (padded rows)
constexpr int NSLOT = 128;             // scattered atomicMax slots

// scalar slot indices (at base of ws, as u32/f32); maxy slots at [16, 16+NSLOT)
#define SL_MAXW1 0
#define SL_MAXW2 1
#define SL_S1    4
#define SL_BERF  5
#define SL_CERF  6
#define SL_SHIFT 7
#define SL_S2    8
#define SL_SA    9
#define SL_SOUT2 10
#define SL_SW1   11
#define SL_SW2   12
#define SL_MAXY0 16

typedef int v4i __attribute__((ext_vector_type(4)));

#define GLD_LDS(g, l) \
  __builtin_amdgcn_global_load_lds((const __attribute__((address_space(1))) void*)(g), \
                                   (__attribute__((address_space(3))) void*)(l), 16, 0, 0)

__global__ void k_init(unsigned* sl) {
  int t = threadIdx.x;
  if (t < 16 + NSLOT) sl[t] = 0u;
}

// grid-stride absmax of a f32 array (n divisible by 4) -> atomicMax on float bits
__global__ void k_absmax(const float* __restrict__ src, int n4, unsigned* slot) {
  const float4* s4 = (const float4*)src;
  float m = 0.f;
  for (int i = blockIdx.x * blockDim.x + threadIdx.x; i < n4; i += gridDim.x * blockDim.x) {
    float4 v = s4[i];
    m = fmaxf(m, fmaxf(fmaxf(fabsf(v.x), fabsf(v.y)), fmaxf(fabsf(v.z), fabsf(v.w))));
  }
  #pragma unroll
  for (int off = 32; off; off >>= 1) m = fmaxf(m, __shfl_down(m, off, 64));
  __shared__ float wm[4];
  int lane = threadIdx.x & 63, wid = threadIdx.x >> 6;
  if (lane == 0) wm[wid] = m;
  __syncthreads();
  if (threadIdx.x == 0) {
    float b = wm[0];
    for (int i = 1; i < (int)(blockDim.x >> 6); i++) b = fmaxf(b, wm[i]);
    atomicMax(slot, __float_as_uint(b));
  }
}

// Mirror the reference's f32 scalar math exactly (op order matters for floor/round).
__global__ void k_scalars1(unsigned* slu, const float* s_x_ptr) {
  float* slf = (float*)slu;
  float s_w1 = __uint_as_float(slu[SL_MAXW1]) / 127.0f;
  float s_w2 = __uint_as_float(slu[SL_MAXW2]) / 127.0f;
  float s1  = s_x_ptr[0] * s_w1;                    // s_out of linear1
  float sfe = s1 / 1.4142f;                         // sf / K_SQRT2
  float berf = floorf(-1.769f / sfe);               // COEF_B / sf
  float cerf = floorf(((float)(1.0 / -0.2888)) / (sfe * sfe)); // COEF_C / sf^2
  float sig  = ((sfe * sfe) * -0.2888f) * 16384.0f; // sf^2*COEF_A * 2^14
  float shiftv = floorf(1.0f / sig);
  float s2 = (s1 * sig) / 2.0f;
  slf[SL_S1] = s1; slf[SL_BERF] = berf; slf[SL_CERF] = cerf;
  slf[SL_SHIFT] = shiftv; slf[SL_S2] = s2; slf[SL_SW1] = s_w1; slf[SL_SW2] = s_w2;
}

__global__ void k_scalars2(unsigned* slu, float* dout_scalar) {
  float* slf = (float*)slu;
  float maxy = 0.f;
  for (int i = 0; i < NSLOT; i++) maxy = fmaxf(maxy, __uint_as_float(slu[SL_MAXY0 + i]));
  float xm = fabsf(maxy * slf[SL_S2]);   // max |x_hat| (rounding is monotone -> max commutes)
  float sa = xm / 127.0f;
  float sout2 = sa * slf[SL_SW2];
  slf[SL_SA] = sa; slf[SL_SOUT2] = sout2;
  *dout_scalar = sout2;                  // second reference output (scalar s)
}

// float4 in -> 4 packed int8 out (n divisible by 4)
__global__ void k_quant_w(const float* __restrict__ w, int8_t* __restrict__ wq, int n4,
                          const unsigned* __restrict__ slu, int swslot) {
  float sw = ((const float*)slu)[swslot];
  const float4* w4 = (const float4*)w;
  for (int i = blockIdx.x * blockDim.x + threadIdx.x; i < n4; i += gridDim.x * blockDim.x) {
    float4 v = w4[i];
    int qa = (int)fminf(fmaxf(rintf(v.x / sw), -127.f), 127.f);
    int qb = (int)fminf(fmaxf(rintf(v.y / sw), -127.f), 127.f);
    int qc = (int)fminf(fmaxf(rintf(v.z / sw), -127.f), 127.f);
    int qd = (int)fminf(fmaxf(rintf(v.w / sw), -127.f), 127.f);
    ((unsigned*)wq)[i] = (unsigned)(qa & 0xff) | ((unsigned)(qb & 0xff) << 8) |
                         ((unsigned)(qc & 0xff) << 16) | ((unsigned)(qd & 0xff) << 24);
  }
}

// int32x4 in -> 4 packed int8 out, zero-fill pad region (sizes divisible by 4)
__global__ void k_cvt_x(const int* __restrict__ x, int8_t* __restrict__ xq, int n4, int npad4) {
  const int4* x4 = (const int4*)x;
  for (int i = blockIdx.x * blockDim.x + threadIdx.x; i < npad4; i += gridDim.x * blockDim.x) {
    unsigned p = 0u;
    if (i < n4) {
      int4 v = x4[i];
      p = (unsigned)(v.x & 0xff) | ((unsigned)(v.y & 0xff) << 8) |
          ((unsigned)(v.z & 0xff) << 16) | ((unsigned)(v.w & 0xff) << 24);
    }
    ((unsigned*)xq)[i] = p;
  }
}

// i8 GEMM, 256x128 tile, BK=128, XOR-swizzled LDS (conflict-free ds_read_b128).
// Plain 2D grid (bn = x fastest) — round-4 mapping; XCD slab swizzle regressed (r5).
// 4 waves stacked in M: wave w owns rows [w*64, w*64+64), all 128 N cols.
// MFMA called swapped mfma(bf,af): acc[i][j] reg r is a COLUMN:
//   m = w*64+i*16+lm,  n = j*16+quad*4+r.
// MODE 0: GEMM1 + IntGELU -> block-reduced absmax(y) -> 1 atomic into 128 slots
// MODE 1: GEMM1 + IntGELU -> requant -> q int8, coalesced via LDS tile
// MODE 2: GEMM2 + bias     -> f32 out, float4 stores
template <int K, int MODE>
__global__ __launch_bounds__(256) void k_gemm(
    const int8_t* __restrict__ A, const int8_t* __restrict__ Bm,
    const float* __restrict__ bias, const unsigned* __restrict__ slu,
    int8_t* __restrict__ qout, float* __restrict__ fout, unsigned* maxslot,
    int Mreal, int Ncols) {
  __shared__ alignas(16) int8_t smem[49152];   // As 32KB + Bs 16KB
  int8_t* As = smem;
  int8_t* Bs = smem + 32768;
  const int t = threadIdx.x;
  const int bn = blockIdx.x, bm = blockIdx.y;
  const int lane = t & 63, wid = t >> 6;
  const int wR = wid * 64;                     // wave's row base within 256-tile
  const int lm = lane & 15, quad = lane >> 4;

  v4i acc[4][8] = {};

  const size_t aBase = (size_t)bm * 256 * K;
  const size_t bBase = (size_t)bn * 128 * K;

  for (int k0 = 0; k0 < K; k0 += 128) {
    #pragma unroll
    for (int c = 0; c < 8; c++) {              // A: 256x128 = 2048 chunks
      int s = c * 256 + t;
      int row = s >> 3;
      int cb = (s & 7) ^ (row & 7);            // XOR swizzle
      GLD_LDS(A + aBase + (size_t)row * K + k0 + cb * 16, As + s * 16);
    }
    #pragma unroll
    for (int c = 0; c < 4; c++) {              // B: 128x128 = 1024 chunks
      int s = c * 256 + t;
      int row = s >> 3;
      int cb = (s & 7) ^ (row & 7);
      GLD_LDS(Bm + bBase + (size_t)row * K + k0 + cb * 16, Bs + s * 16);
    }
    __syncthreads();
    #pragma unroll
    for (int ks = 0; ks < 2; ks++) {           // two k=64 sub-steps
      v4i af[4], bf[8];
      #pragma unroll
      for (int i = 0; i < 4; i++) {
        int r = wR + i * 16 + lm;
        af[i] = *(const v4i*)(As + r * 128 + (((ks * 4 + quad) ^ (r & 7)) << 4));
      }
      #pragma unroll
      for (int j = 0; j < 8; j++) {
        int r = j * 16 + lm;
        bf[j] = *(const v4i*)(Bs + r * 128 + (((ks * 4 + quad) ^ (r & 7)) << 4));
      }
      #pragma unroll
      for (int i = 0; i < 4; i++)
        #pragma unroll
        for (int j = 0; j < 8; j++)
          acc[i][j] = __builtin_amdgcn_mfma_i32_16x16x64_i8(bf[j], af[i], acc[i][j], 0, 0, 0);
    }
    __syncthreads();
  }

  const float* slf = (const float*)slu;
  if constexpr (MODE == 2) {
    float sout2 = slf[SL_SOUT2];
    float4 bq[8];                              // hoisted: quantized bias per j
    #pragma unroll
    for (int j = 0; j < 8; j++) {
      float4 bv = *(const float4*)(bias + bn * 128 + j * 16 + quad * 4);
      bq[j].x = rintf(bv.x / sout2); bq[j].y = rintf(bv.y / sout2);
      bq[j].z = rintf(bv.z / sout2); bq[j].w = rintf(bv.w / sout2);
    }
    #pragma unroll
    for (int i = 0; i < 4; i++) {
      int gr = bm * 256 + wR + i * 16 + lm;
      if (gr < Mreal) {
        #pragma unroll
        for (int j = 0; j < 8; j++) {
          int gc0 = bn * 128 + j * 16 + quad * 4;
          float4 o;
          o.x = (float)acc[i][j][0] + bq[j].x;
          o.y = (float)acc[i][j][1] + bq[j].y;
          o.z = (float)acc[i][j][2] + bq[j].z;
          o.w = (float)acc[i][j][3] + bq[j].w;
          *(float4*)(fout + (size_t)gr * Ncols + gc0) = o;
        }
      }
    }
  } else {
    float s1 = slf[SL_S1], berf = slf[SL_BERF], cerf = slf[SL_CERF], shiftv = slf[SL_SHIFT];
    float s2 = slf[SL_S2];
    float sa = (MODE == 1) ? slf[SL_SA] : 1.0f;
    float r_req = (MODE == 1) ? (s2 / sa) : 1.0f;
    float lmax = 0.f;
    float4 bq[8];                              // hoisted: rintf(bias/s1) per j
    #pragma unroll
    for (int j = 0; j < 8; j++) {
      float4 bv = *(const float4*)(bias + bn * 128 + j * 16 + quad * 4);
      bq[j].x = rintf(bv.x / s1); bq[j].y = rintf(bv.y / s1);
      bq[j].z = rintf(bv.z / s1); bq[j].w = rintf(bv.w / s1);
    }
    #pragma unroll
    for (int i = 0; i < 4; i++) {
      int mrow = wR + i * 16 + lm;
      int gr = bm * 256 + mrow;
      bool rowok = gr < Mreal;
      #pragma unroll
      for (int j = 0; j < 8; j++) {
        int n0 = j * 16 + quad * 4;
        unsigned packed = 0u;
        #pragma unroll
        for (int r = 0; r < 4; r++) {
          float a = (float)acc[i][j][r] + ((const float*)&bq[j])[r]; // exact (<2^24)
          float sgn = (a > 0.f) ? 1.f : ((a < 0.f) ? -1.f : 0.f);
          float ax = fminf(fabsf(a), -berf);
          float tt = ax + berf;
          float yv = sgn * (tt * tt + cerf);
          yv = floorf(yv * (1.0f / 16384.0f));                  // floor(y / 2^14), exact scale
          float y = a * (yv + shiftv);                          // y_int
          if constexpr (MODE == 0) {
            if (rowok) lmax = fmaxf(lmax, fabsf(y));
          } else {
            float qf = rintf(y * r_req);
            qf = fminf(fmaxf(qf, -128.f), 127.f);
            packed |= ((unsigned)((int)qf & 0xff)) << (8 * r);
          }
        }
        if constexpr (MODE == 1) {
          // LDS tile [256][132] (pad 4 de-banks); dword = 4 consecutive cols
          *(unsigned*)(smem + mrow * 132 + n0) = packed;
        }
      }
    }
    if constexpr (MODE == 0) {
      #pragma unroll
      for (int off = 32; off; off >>= 1) lmax = fmaxf(lmax, __shfl_down(lmax, off, 64));
      float* red = (float*)smem;
      if (lane == 0) red[wid] = lmax;
      __syncthreads();
      if (t == 0) {
        float b = fmaxf(fmaxf(red[0], red[1]), fmaxf(red[2], red[3]));
        int id = blockIdx.y * gridDim.x + blockIdx.x;
        atomicMax(maxslot + (id & (NSLOT - 1)), __float_as_uint(b));
      }
    } else {
      __syncthreads();
      // coalesced store of the 256x128 int8 tile: 8 x 1KB per wave
      #pragma unroll
      for (int c2 = 0; c2 < 8; c2++) {
        int idx = c2 * 256 + t;
        int row = idx >> 3, c16 = (idx & 7) << 4;
        v4i v = *(const v4i*)(smem + row * 132 + c16);
        *(v4i*)(qout + (size_t)(bm * 256 + row) * Ncols + bn * 128 + c16) = v;
      }
    }
  }
}

extern "C" void kernel_launch(void* const* d_in, const int* in_sizes, int n_in,
                              void* d_out, int out_size, void* d_ws, size_t ws_size,
                              hipStream_t stream) {
  const int*   x   = (const int*)d_in[0];
  const float* s_x = (const float*)d_in[1];
  const float* w1  = (const float*)d_in[2];
  const float* b1  = (const float*)d_in[3];
  const float* w2  = (const float*)d_in[4];
  const float* b2  = (const float*)d_in[5];
  float* out = (float*)d_out;

  char* ws = (char*)d_ws;
  unsigned* slots = (unsigned*)ws;
  int8_t* w1q = (int8_t*)(ws + 1024);
  int8_t* w2q = w1q + (size_t)Hh * Dd;
  int8_t* xq  = w2q + (size_t)Dd * Hh;
  int8_t* qbuf = xq + (size_t)Mpad * Dd;   // total ws use ~74 MB

  k_init<<<1, 256, 0, stream>>>(slots);
  k_absmax<<<512, 256, 0, stream>>>(w1, Hh * Dd / 4, slots + SL_MAXW1);
  k_absmax<<<512, 256, 0, stream>>>(w2, Dd * Hh / 4, slots + SL_MAXW2);
  k_scalars1<<<1, 1, 0, stream>>>(slots, s_x);
  k_quant_w<<<512, 256, 0, stream>>>(w1, w1q, Hh * Dd / 4, slots, SL_SW1);
  k_quant_w<<<512, 256, 0, stream>>>(w2, w2q, Dd * Hh / 4, slots, SL_SW2);
  k_cvt_x<<<512, 256, 0, stream>>>(x, xq, M * Dd / 4, Mpad * Dd / 4);

  dim3 g1(Hh / 128, MT2);   // 32 x 50
  // pass 0: GEMM1+GELU -> max|y| (1 atomic/block into 128 slots)
  k_gemm<Dd, 0><<<g1, 256, 0, stream>>>(xq, w1q, b1, slots, nullptr, nullptr,
                                        slots + SL_MAXY0, M, Hh);
  k_scalars2<<<1, 1, 0, stream>>>(slots, out + (size_t)M * Dd);
  // pass 1: GEMM1+GELU -> requant -> q (coalesced via LDS tile)
  k_gemm<Dd, 1><<<g1, 256, 0, stream>>>(xq, w1q, b1, slots, qbuf, nullptr,
                                        nullptr, M, Hh);
  dim3 g2(Dd / 128, MT2);   // 8 x 50
  // GEMM2 + bias -> out (float4 stores)
  k_gemm<Hh, 2><<<g2, 256, 0, stream>>>(qbuf, w2q, b2, slots, nullptr, out,
                                        nullptr, M, Dd);
}

// Round 7
// 370.269 us; speedup vs baseline: 1.5753x; 1.5753x over previous
//
#include <hip/hip_runtime.h>
#include <cstdint>
#include <cstddef>

// Problem sizes (fixed by the reference)
constexpr int Bb = 64, Ss = 197, Dd = 1024, Hh = 4096;
constexpr int M  = Bb * Ss;            // 12608 tokens
constexpr int MT = (M + 127) / 128;    // 99 M-tiles
constexpr int Mpad = MT * 128;         // 12672 (padded rows)
constexpr int NBLK1 = (Hh / 128) * MT; // 3168 GEMM1 blocks

// ws layout: slots u32[64] @0 | pmax_w f32[1024] @1024 | pmax_y f32[NBLK1] @8192 | data @32768
#define SL_S1    4
#define SL_BERF  5
#define SL_CERF  6
#define SL_SHIFT 7
#define SL_S2    8
#define SL_SA    9
#define SL_SOUT2 10
#define SL_SW1   11
#define SL_SW2   12

typedef int v4i __attribute__((ext_vector_type(4)));

#define GLD_LDS(g, l) \
  __builtin_amdgcn_global_load_lds((const __attribute__((address_space(1))) void*)(g), \
                                   (__attribute__((address_space(3))) void*)(l), 16, 0, 0)

__device__ __forceinline__ float blockmax256(float m) {
  #pragma unroll
  for (int off = 32; off; off >>= 1) m = fmaxf(m, __shfl_down(m, off, 64));
  __shared__ float wm[4];
  int lane = threadIdx.x & 63, wid = threadIdx.x >> 6;
  if (lane == 0) wm[wid] = m;
  __syncthreads();
  return fmaxf(fmaxf(wm[0], wm[1]), fmaxf(wm[2], wm[3]));
}

// blocks [0,512): w1 partial max; [512,1024): w2. Plain stores, no init needed.
__global__ void k_wmax(const float* __restrict__ w1, const float* __restrict__ w2,
                       int n4, float* __restrict__ pmax) {
  int b = blockIdx.x;
  const float4* s4 = (const float4*)(b < 512 ? w1 : w2);
  float m = 0.f;
  for (int i = (b & 511) * 256 + threadIdx.x; i < n4; i += 512 * 256) {
    float4 v = s4[i];
    m = fmaxf(m, fmaxf(fmaxf(fabsf(v.x), fabsf(v.y)), fmaxf(fabsf(v.z), fabsf(v.w))));
  }
  m = blockmax256(m);
  if (threadIdx.x == 0) pmax[b] = m;
}

// Reduce pmax_w -> s_w1/s_w2, then mirror the reference's f32 scalar math exactly.
__global__ void k_scalars1(unsigned* slu, const float* __restrict__ pmax,
                           const float* __restrict__ s_x_ptr) {
  int t = threadIdx.x;
  float m1 = fmaxf(pmax[t], pmax[t + 256]);
  float m2 = fmaxf(pmax[512 + t], pmax[768 + t]);
  // reduce m1,m2 across 256 threads via LDS
  __shared__ float r1[256], r2[256];
  r1[t] = m1; r2[t] = m2;
  __syncthreads();
  for (int s = 128; s; s >>= 1) {
    if (t < s) { r1[t] = fmaxf(r1[t], r1[t + s]); r2[t] = fmaxf(r2[t], r2[t + s]); }
    __syncthreads();
  }
  if (t == 0) {
    float* slf = (float*)slu;
    float s_w1 = r1[0] / 127.0f;
    float s_w2 = r2[0] / 127.0f;
    float s1  = s_x_ptr[0] * s_w1;                    // s_out of linear1
    float sfe = s1 / 1.4142f;                         // sf / K_SQRT2
    float berf = floorf(-1.769f / sfe);               // COEF_B / sf
    float cerf = floorf(((float)(1.0 / -0.2888)) / (sfe * sfe)); // COEF_C / sf^2
    float sig  = ((sfe * sfe) * -0.2888f) * 16384.0f; // sf^2*COEF_A * 2^14
    float shiftv = floorf(1.0f / sig);
    float s2 = (s1 * sig) / 2.0f;
    slf[SL_S1] = s1; slf[SL_BERF] = berf; slf[SL_CERF] = cerf;
    slf[SL_SHIFT] = shiftv; slf[SL_S2] = s2; slf[SL_SW1] = s_w1; slf[SL_SW2] = s_w2;
  }
}

// Reduce pmax_y (NBLK1 plain-stored block maxima) -> sa/sout2 + output scalar.
__global__ void k_scalars2(unsigned* slu, const float* __restrict__ pmax,
                           float* dout_scalar) {
  int t = threadIdx.x;
  float m = 0.f;
  for (int i = t; i < NBLK1; i += 256) m = fmaxf(m, pmax[i]);
  __shared__ float r1[256];
  r1[t] = m;
  __syncthreads();
  for (int s = 128; s; s >>= 1) {
    if (t < s) r1[t] = fmaxf(r1[t], r1[t + s]);
    __syncthreads();
  }
  if (t == 0) {
    float* slf = (float*)slu;
    float xm = fabsf(r1[0] * slf[SL_S2]);  // max |x_hat| (rounding monotone -> max commutes)
    float sa = xm / 127.0f;
    float sout2 = sa * slf[SL_SW2];
    slf[SL_SA] = sa; slf[SL_SOUT2] = sout2;
    *dout_scalar = sout2;                  // second reference output (scalar s)
  }
}

// Fused: quantize w1, w2 (float4 -> 4x int8) and convert/zero-pad x (int4 -> 4x int8).
__global__ void k_quantcvt(const float* __restrict__ w1, const float* __restrict__ w2,
                           const int* __restrict__ x, const unsigned* __restrict__ slu,
                           int8_t* __restrict__ w1q, int8_t* __restrict__ w2q,
                           int8_t* __restrict__ xq) {
  const float* slf = (const float*)slu;
  float sw1 = slf[SL_SW1], sw2 = slf[SL_SW2];
  const int n1 = Hh * Dd / 4, n2 = Dd * Hh / 4;
  const int nx = M * Dd / 4, n3 = Mpad * Dd / 4;
  const int total = n1 + n2 + n3;
  for (int i = blockIdx.x * blockDim.x + threadIdx.x; i < total; i += gridDim.x * blockDim.x) {
    if (i < n1 + n2) {
      bool first = i < n1;
      int idx = first ? i : i - n1;
      float sw = first ? sw1 : sw2;
      float4 v = ((const float4*)(first ? w1 : w2))[idx];
      int qa = (int)fminf(fmaxf(rintf(v.x / sw), -127.f), 127.f);
      int qb = (int)fminf(fmaxf(rintf(v.y / sw), -127.f), 127.f);
      int qc = (int)fminf(fmaxf(rintf(v.z / sw), -127.f), 127.f);
      int qd = (int)fminf(fmaxf(rintf(v.w / sw), -127.f), 127.f);
      unsigned p = (unsigned)(qa & 0xff) | ((unsigned)(qb & 0xff) << 8) |
                   ((unsigned)(qc & 0xff) << 16) | ((unsigned)(qd & 0xff) << 24);
      ((unsigned*)(first ? w1q : w2q))[idx] = p;
    } else {
      int idx = i - n1 - n2;
      unsigned p = 0u;
      if (idx < nx) {
        int4 v = ((const int4*)x)[idx];
        p = (unsigned)(v.x & 0xff) | ((unsigned)(v.y & 0xff) << 8) |
            ((unsigned)(v.z & 0xff) << 16) | ((unsigned)(v.w & 0xff) << 24);
      }
      ((unsigned*)xq)[idx] = p;
    }
  }
}

// i8 GEMM, 128x128 tile, BK=128, XOR-swizzled LDS (conflict-free ds_read_b128).
// Plain 2D grid (R4 mapping — proven fastest). MFMA swapped mfma(bf,af): acc[i][j]
// reg r is a COLUMN: m = wRow+i*16+lm, n = wCol+j*16+quad*4+r.
// MODE 0: GEMM1 + IntGELU -> block max|y| -> plain store pmax_y[bid]
// MODE 1: GEMM1 + IntGELU -> requant -> q int8, coalesced via LDS tile
// MODE 2: GEMM2 + bias     -> f32 out, float4 stores
template <int K, int MODE>
__global__ __launch_bounds__(256) void k_gemm(
    const int8_t* __restrict__ A, const int8_t* __restrict__ Bm,
    const float* __restrict__ bias, const unsigned* __restrict__ slu,
    int8_t* __restrict__ qout, float* __restrict__ fout, float* __restrict__ pmax_y,
    int Mreal, int Ncols) {
  __shared__ alignas(16) int8_t smem[32768];
  int8_t* As = smem;
  int8_t* Bs = smem + 16384;
  const int t = threadIdx.x;
  const int bm = blockIdx.y, bn = blockIdx.x;
  const int lane = t & 63, wid = t >> 6;
  const int wRow = (wid >> 1) * 64, wCol = (wid & 1) * 64;
  const int lm = lane & 15, quad = lane >> 4;

  v4i acc[4][4] = {};

  const size_t aBase = (size_t)bm * 128 * K;
  const size_t bBase = (size_t)bn * 128 * K;

  for (int k0 = 0; k0 < K; k0 += 128) {
    #pragma unroll
    for (int c = 0; c < 4; c++) {
      int s = c * 256 + t;                 // LDS chunk slot 0..1023 (16B chunks)
      int row = s >> 3;
      int cb = (s & 7) ^ (row & 7);        // XOR swizzle: global chunk col for this slot
      size_t goff = (size_t)row * K + k0 + cb * 16;
      GLD_LDS(A + aBase + goff, As + s * 16);
      GLD_LDS(Bm + bBase + goff, Bs + s * 16);
    }
    __syncthreads();
    #pragma unroll
    for (int ks = 0; ks < 2; ks++) {       // two k=64 sub-steps
      v4i af[4], bf[4];
      #pragma unroll
      for (int i = 0; i < 4; i++) {
        int r = wRow + i * 16 + lm;
        af[i] = *(const v4i*)(As + r * 128 + (((ks * 4 + quad) ^ (r & 7)) << 4));
      }
      #pragma unroll
      for (int i = 0; i < 4; i++) {
        int r = wCol + i * 16 + lm;
        bf[i] = *(const v4i*)(Bs + r * 128 + (((ks * 4 + quad) ^ (r & 7)) << 4));
      }
      #pragma unroll
      for (int i = 0; i < 4; i++)
        #pragma unroll
        for (int j = 0; j < 4; j++)
          acc[i][j] = __builtin_amdgcn_mfma_i32_16x16x64_i8(bf[j], af[i], acc[i][j], 0, 0, 0);
    }
    __syncthreads();
  }

  const float* slf = (const float*)slu;
  if constexpr (MODE == 2) {
    float sout2 = slf[SL_SOUT2];
    float4 bq[4];                           // hoisted: quantized bias per j
    #pragma unroll
    for (int j = 0; j < 4; j++) {
      float4 bv = *(const float4*)(bias + bn * 128 + wCol + j * 16 + quad * 4);
      bq[j].x = rintf(bv.x / sout2); bq[j].y = rintf(bv.y / sout2);
      bq[j].z = rintf(bv.z / sout2); bq[j].w = rintf(bv.w / sout2);
    }
    #pragma unroll
    for (int i = 0; i < 4; i++) {
      int gr = bm * 128 + wRow + i * 16 + lm;
      if (gr < Mreal) {
        #pragma unroll
        for (int j = 0; j < 4; j++) {
          int gc0 = bn * 128 + wCol + j * 16 + quad * 4;
          float4 o;
          o.x = (float)acc[i][j][0] + bq[j].x;
          o.y = (float)acc[i][j][1] + bq[j].y;
          o.z = (float)acc[i][j][2] + bq[j].z;
          o.w = (float)acc[i][j][3] + bq[j].w;
          *(float4*)(fout + (size_t)gr * Ncols + gc0) = o;
        }
      }
    }
  } else {
    float s1 = slf[SL_S1], berf = slf[SL_BERF], cerf = slf[SL_CERF], shiftv = slf[SL_SHIFT];
    float s2 = slf[SL_S2];
    float sa = (MODE == 1) ? slf[SL_SA] : 1.0f;
    float r_req = (MODE == 1) ? (s2 / sa) : 1.0f;
    float lmax = 0.f;
    float4 bq[4];                           // hoisted: rintf(bias/s1) per j
    #pragma unroll
    for (int j = 0; j < 4; j++) {
      float4 bv = *(const float4*)(bias + bn * 128 + wCol + j * 16 + quad * 4);
      bq[j].x = rintf(bv.x / s1); bq[j].y = rintf(bv.y / s1);
      bq[j].z = rintf(bv.z / s1); bq[j].w = rintf(bv.w / s1);
    }
    #pragma unroll
    for (int i = 0; i < 4; i++) {
      int mrow = wRow + i * 16 + lm;
      int gr = bm * 128 + mrow;
      bool rowok = gr < Mreal;
      #pragma unroll
      for (int j = 0; j < 4; j++) {
        int n0 = wCol + j * 16 + quad * 4;
        unsigned packed = 0u;
        #pragma unroll
        for (int r = 0; r < 4; r++) {
          float a = (float)acc[i][j][r] + ((const float*)&bq[j])[r]; // exact (<2^24)
          float ax = fminf(fabsf(a), -berf);
          float tt = ax + berf;
          float u = tt * tt + cerf;          // always < 0 (|cerf| > berf^2 - |cerf|... proven)
          // sign trick: ref is sign(a)*u; at a==0 the value is annihilated by y=a*(..)
          float ye = (a < 0.f) ? -u : u;
          float yv = floorf(ye * (1.0f / 16384.0f));            // floor(y / 2^14), exact scale
          float y = a * (yv + shiftv);                          // y_int
          if constexpr (MODE == 0) {
            if (rowok) lmax = fmaxf(lmax, fabsf(y));
          } else {
            float qf = rintf(y * r_req);
            qf = fminf(fmaxf(qf, -128.f), 127.f);
            packed |= ((unsigned)((int)qf & 0xff)) << (8 * r);
          }
        }
        if constexpr (MODE == 1) {
          // LDS tile [128][132] (pad 4 de-banks); dword = 4 consecutive cols
          *(unsigned*)(smem + mrow * 132 + n0) = packed;
        }
      }
    }
    if constexpr (MODE == 0) {
      #pragma unroll
      for (int off = 32; off; off >>= 1) lmax = fmaxf(lmax, __shfl_down(lmax, off, 64));
      float* red = (float*)smem;
      if (lane == 0) red[wid] = lmax;
      __syncthreads();
      if (t == 0) {
        float b = fmaxf(fmaxf(red[0], red[1]), fmaxf(red[2], red[3]));
        pmax_y[bm * gridDim.x + bn] = b;    // plain store — no atomics, no init
      }
    } else {
      __syncthreads();
      // coalesced store of the 128x128 int8 tile: 4 x 1KB per wave
      #pragma unroll
      for (int c2 = 0; c2 < 4; c2++) {
        int idx = c2 * 256 + t;
        int row = idx >> 3, c16 = (idx & 7) << 4;
        v4i v = *(const v4i*)(smem + row * 132 + c16);
        *(v4i*)(qout + (size_t)(bm * 128 + row) * Ncols + bn * 128 + c16) = v;
      }
    }
  }
}

extern "C" void kernel_launch(void* const* d_in, const int* in_sizes, int n_in,
                              void* d_out, int out_size, void* d_ws, size_t ws_size,
                              hipStream_t stream) {
  const int*   x   = (const int*)d_in[0];
  const float* s_x = (const float*)d_in[1];
  const float* w1  = (const float*)d_in[2];
  const float* b1  = (const float*)d_in[3];
  const float* w2  = (const float*)d_in[4];
  const float* b2  = (const float*)d_in[5];
  float* out = (float*)d_out;

  char* ws = (char*)d_ws;
  unsigned* slots = (unsigned*)ws;
  float* pmax_w = (float*)(ws + 1024);
  float* pmax_y = (float*)(ws + 8192);
  int8_t* w1q = (int8_t*)(ws + 32768);
  int8_t* w2q = w1q + (size_t)Hh * Dd;
  int8_t* xq  = w2q + (size_t)Dd * Hh;
  int8_t* qbuf = xq + (size_t)Mpad * Dd;   // total ws use ~73 MB

  k_wmax<<<1024, 256, 0, stream>>>(w1, w2, Hh * Dd / 4, pmax_w);
  k_scalars1<<<1, 256, 0, stream>>>(slots, pmax_w, s_x);
  k_quantcvt<<<1024, 256, 0, stream>>>(w1, w2, x, slots, w1q, w2q, xq);

  dim3 g1(Hh / 128, MT);   // 32 x 99
  // pass 0: GEMM1+GELU -> per-block max|y| (plain stores)
  k_gemm<Dd, 0><<<g1, 256, 0, stream>>>(xq, w1q, b1, slots, nullptr, nullptr,
                                        pmax_y, M, Hh);
  k_scalars2<<<1, 256, 0, stream>>>(slots, pmax_y, out + (size_t)M * Dd);
  // pass 1: GEMM1+GELU -> requant -> q (coalesced via LDS tile)
  k_gemm<Dd, 1><<<g1, 256, 0, stream>>>(xq, w1q, b1, slots, qbuf, nullptr,
                                        nullptr, M, Hh);
  dim3 g2(Dd / 128, MT);   // 8 x 99
  // GEMM2 + bias -> out (float4 stores)
  k_gemm<Hh, 2><<<g2, 256, 0, stream>>>(qbuf, w2q, b2, slots, nullptr, out,
                                        nullptr, M, Dd);
}